// Round 12
// baseline (135.602 us; speedup 1.0000x reference)
//
#include <hip/hip_runtime.h>
#include <hip/hip_bf16.h>

// ProjectionAggregating: B=4096, N=64, D=128
// out[b,d] = query_emb + final_refer / (1e-9 + ref_norm/query_norm*2.5)
// final_refer[b,d] = sum_n (h1@W2^T + b2)[b,n,d] * (refer_embs - start_embs*refer_r)[b,n,d]
// h1 = relu(query_r@W1a^T + refer_r@W1b^T + b1)   (W1a = W1[:, :128], W1b = W1[:, 128:])

typedef __attribute__((ext_vector_type(8))) short bf16x8;   // 8 bf16 = 4 VGPRs (MFMA A/B frag)
typedef __attribute__((ext_vector_type(4))) float f32x4;    // MFMA C/D frag

// lgkm-only barrier: LDS producer->consumer ordering WITHOUT draining vmcnt
// (global_load_lds prefetch must stay in flight across it). Proven R7/R11.
#define WG_BARRIER()                                            \
    do {                                                        \
        asm volatile("s_waitcnt lgkmcnt(0)" ::: "memory");      \
        __builtin_amdgcn_s_barrier();                           \
    } while (0)

// counted vmem wait (T4): N newest vmem ops may stay outstanding.
#define VWAIT(n)                                                        \
    do {                                                                \
        asm volatile("s_waitcnt vmcnt(" #n ")" ::: "memory");           \
        __builtin_amdgcn_sched_barrier(0);                              \
    } while (0)

__device__ __forceinline__ unsigned short f2bf(float x) {      // RNE
    unsigned int u = __float_as_uint(x);
    u += 0x7FFFu + ((u >> 16) & 1u);
    return (unsigned short)(u >> 16);
}
__device__ __forceinline__ float bf2f(unsigned short h) {
    return __uint_as_float(((unsigned int)h) << 16);
}
// pack two f32 -> two bf16 (round-half-up; inputs finite randn; R9/R11-validated class)
__device__ __forceinline__ unsigned int pack2bf(float lo, float hi) {
    unsigned int ulo = __float_as_uint(lo) + 0x8000u;
    unsigned int uhi = __float_as_uint(hi) + 0x8000u;
    return (ulo >> 16) | (uhi & 0xFFFF0000u);
}

// ---- kernel 1: convert W1b (W1[:,128:256]) and W2 to bf16 into workspace ----
__global__ __launch_bounds__(256) void pa_prep(const float* __restrict__ W1,
                                               const float* __restrict__ W2,
                                               unsigned short* __restrict__ w1b,
                                               unsigned short* __restrict__ w2b) {
    int i = blockIdx.x * 256 + threadIdx.x;   // grid covers 32768
    if (i < 16384) {
        int d = i >> 7, k = i & 127;
        w1b[i] = f2bf(W1[d * 256 + 128 + k]);
    } else {
        int j = i - 16384;
        w2b[j] = f2bf(W2[j]);
    }
}

// ---- kernel 2: qv[b,d] = b1[d] + sum_k query_r[b,k] * W1[d,k]  (f32, exact) ----
__global__ __launch_bounds__(256) void pa_qv(const float* __restrict__ query_r,
                                             const float* __restrict__ W1,
                                             const float* __restrict__ b1,
                                             float* __restrict__ qv) {
    __shared__ float wa[128][129];
    __shared__ float sq[32][128];
    const int tid = threadIdx.x;
    const int b0 = blockIdx.x * 32;  // grid = 128 blocks

    for (int i = tid; i < 128 * 128; i += 256) {
        int d = i >> 7, k = i & 127;
        wa[d][k] = W1[d * 256 + k];
    }
    for (int i = tid; i < 32 * 128; i += 256) {
        sq[i >> 7][i & 127] = query_r[(size_t)b0 * 128 + i];
    }
    __syncthreads();

    const int d = tid & 127;
    const int rb = (tid >> 7) * 16;
    const float bb = b1[d];
    for (int j = 0; j < 16; ++j) {
        int r = rb + j;
        float a0 = 0.f, a1 = 0.f, a2 = 0.f, a3 = 0.f;
        #pragma unroll
        for (int k = 0; k < 128; k += 4) {
            a0 += sq[r][k + 0] * wa[d][k + 0];
            a1 += sq[r][k + 1] * wa[d][k + 1];
            a2 += sq[r][k + 2] * wa[d][k + 2];
            a3 += sq[r][k + 3] * wa[d][k + 3];
        }
        qv[(size_t)(b0 + r) * 128 + d] = bb + ((a0 + a1) + (a2 + a3));
    }
}

// ---- kernel 3: persistent double-buffered gll pipeline (m201 T3+T4 template) ----
// 256 blocks (1/CU) x 512 threads; block bid owns b in [bid*16, bid*16+16),
// split into 32 tasks of 32 rows. Per task: 6 global_load_lds per thread stage
// r/e/s f32 (48 KB, source-XOR-swizzled). Steady state: issue(t+1) ->
// vmcnt(6) -> barrier -> compute(t). Compute has ZERO compiler vmem (weights
// in regs, qv/qe in LDS), so the counted vmcnt is exact (stores only add
// conservatively). All in-loop barriers are lgkm-only.
__global__ __launch_bounds__(512, 1) void pa_main(
    const float* __restrict__ query_emb,
    const float* __restrict__ refer_embs,
    const float* __restrict__ refer_r,
    const float* __restrict__ start_embs,
    const float* __restrict__ qv,
    const unsigned short* __restrict__ w1b,
    const unsigned short* __restrict__ w2b,
    const float* __restrict__ b2,
    float* __restrict__ out) {
    __shared__ __align__(16) float bufR[2][32 * 128];   // 2 x 16 KB
    __shared__ __align__(16) float bufE[2][32 * 128];   // 2 x 16 KB
    __shared__ __align__(16) float bufS[2][32 * 128];   // 2 x 16 KB
    __shared__ __align__(16) unsigned short sH[32 * 128]; // 8 KB
    __shared__ float sQv[16 * 128];                     // 8 KB
    __shared__ float sQe[16 * 128];                     // 8 KB
    __shared__ float sFin[128];
    __shared__ float sRed[4];
    // total ~120.6 KB -> 1 block/CU, 8 waves

    const int bid  = blockIdx.x;     // 0..255
    const int tid  = threadIdx.x;    // 0..511
    const int lane = tid & 63;
    const int wv   = tid >> 6;       // 0..7; wave owns output cols [wv*16, wv*16+16)
    const int hl   = lane & 15;
    const int qh   = lane >> 4;
    const int col  = wv * 16 + hl;

    const size_t base0 = (size_t)bid * 16 * 8192;   // f32 offset of this block's 16 b's

    // ---- prologue: weights -> registers (once per block), smalls -> LDS ----
    bf16x8 bW[4], bW2[4];
    #pragma unroll
    for (int ks = 0; ks < 4; ++ks) {
        bW[ks]  = *(const bf16x8*)(w1b + (size_t)col * 128 + ks * 32 + qh * 8);
        bW2[ks] = *(const bf16x8*)(w2b + (size_t)col * 128 + ks * 32 + qh * 8);
    }
    const float b2r = b2[col];
    {   // 16 b's of qv and qe: 2048 f32 each
        const float4* gqv = (const float4*)(qv + (size_t)bid * 16 * 128);
        const float4* gqe = (const float4*)(query_emb + (size_t)bid * 16 * 128);
        float4 v1 = gqv[tid];
        float4 v2 = gqe[tid];
        *(float4*)(sQv + tid * 4) = v1;
        *(float4*)(sQe + tid * 4) = v2;
    }
    __syncthreads();   // full drain: vmcnt clean before counted waits

    // ---- gll issue for one task: 6 ops/thread (r,e,s x 2 rounds) ----
    // LDS image[f] = global[row][c ^ (row&7)] at float4 granularity
    // (f = float4 index, row = f>>5, c = f&31): linear LDS dest (wave-uniform
    // base + lane*16), per-lane pre-swizzled SOURCE (rule #21, R8-validated).
    #define ISSUE(bi, t)                                                                    \
        do {                                                                                \
            const int bb_   = (t) >> 1;                                                     \
            const size_t gb = base0 + (size_t)bb_ * 8192 + ((t) & 1) * 4096;                \
            _Pragma("unroll")                                                               \
            for (int k = 0; k < 2; ++k) {                                                   \
                int f = wv * 64 + lane + k * 512;                                           \
                int row = f >> 5, c = f & 31;                                               \
                int srcf = (row * 32 + (c ^ (row & 7))) * 4;                                \
                int dst  = (wv * 64 + k * 512) * 4;                                         \
                __builtin_amdgcn_global_load_lds(                                           \
                    (const __attribute__((address_space(1))) unsigned int*)(refer_r + gb + srcf), \
                    (__attribute__((address_space(3))) unsigned int*)(&bufR[bi][dst]), 16, 0, 0); \
                __builtin_amdgcn_global_load_lds(                                           \
                    (const __attribute__((address_space(1))) unsigned int*)(refer_embs + gb + srcf), \
                    (__attribute__((address_space(3))) unsigned int*)(&bufE[bi][dst]), 16, 0, 0); \
                __builtin_amdgcn_global_load_lds(                                           \
                    (const __attribute__((address_space(1))) unsigned int*)(start_embs + gb + srcf), \
                    (__attribute__((address_space(3))) unsigned int*)(&bufS[bi][dst]), 16, 0, 0); \
            }                                                                               \
        } while (0)

    ISSUE(0, 0);

    float pacc = 0.f;   // per-lane col-partial, accumulated across a b's 2 halves

    #pragma unroll 1
    for (int t = 0; t < 32; ++t) {
        const int cur = t & 1;
        const int bb  = t >> 1;

        if (t < 31) ISSUE(cur ^ 1, t + 1);
        if (t < 31) { VWAIT(6); } else { VWAIT(0); }
        __builtin_amdgcn_s_barrier();   // buf[cur] visible to all waves

        // ---- GEMM1: A = r (f32 LDS, swizzled) packed to bf16; B = W1b regs ----
        f32x4 acc1[2] = {};
        #pragma unroll
        for (int rt = 0; rt < 2; ++rt) {
            const int row = rt * 16 + hl;
            const int sw  = row & 7;
            const float* rp = &bufR[cur][row * 128];
            bf16x8 af[4];
            #pragma unroll
            for (int ks = 0; ks < 4; ++ks) {
                int c0 = ks * 8 + qh * 2;
                float4 fa = *(const float4*)(rp + ((c0    ) ^ sw) * 4);
                float4 fb = *(const float4*)(rp + ((c0 + 1) ^ sw) * 4);
                union { unsigned int u[4]; bf16x8 v; } cv;
                cv.u[0] = pack2bf(fa.x, fa.y);
                cv.u[1] = pack2bf(fa.z, fa.w);
                cv.u[2] = pack2bf(fb.x, fb.y);
                cv.u[3] = pack2bf(fb.z, fb.w);
                af[ks] = cv.v;
            }
            #pragma unroll
            for (int ks = 0; ks < 4; ++ks)
                acc1[rt] = __builtin_amdgcn_mfma_f32_16x16x32_bf16(af[ks], bW[ks], acc1[rt], 0, 0, 0);
        }

        // ---- epi1: h1 = relu(acc1 + qv[col]) -> sH (bf16, XOR-swz) ----
        // C/D: col = lane&15 (+wave offset), row = rt*16 + qh*4 + j
        {
            const float qvv = sQv[bb * 128 + col];
            #pragma unroll
            for (int rt = 0; rt < 2; ++rt) {
                #pragma unroll
                for (int j = 0; j < 4; ++j) {
                    int row = rt * 16 + qh * 4 + j;
                    float h = acc1[rt][j] + qvv;
                    h = h > 0.0f ? h : 0.0f;
                    int byte = row * 256 + ((col * 2) ^ ((row & 7) << 4));
                    *(unsigned short*)((char*)sH + byte) = f2bf(h);
                }
            }
        }
        WG_BARRIER();   // h1 ready (lgkm only -- prefetch keeps flying)

        // ---- GEMM2: A = h1 (bf16 LDS, swz); B = W2 regs ----
        f32x4 acc2[2] = {};
        #pragma unroll
        for (int rt = 0; rt < 2; ++rt) {
            const int row = rt * 16 + hl;
            const int rsw = (row & 7) << 4;
            bf16x8 af2[4];
            #pragma unroll
            for (int ks = 0; ks < 4; ++ks) {
                int byte = row * 256 + ((ks * 64 + qh * 16) ^ rsw);
                af2[ks] = *(const bf16x8*)((const char*)sH + byte);
            }
            #pragma unroll
            for (int ks = 0; ks < 4; ++ks)
                acc2[rt] = __builtin_amdgcn_mfma_f32_16x16x32_bf16(af2[ks], bW2[ks], acc2[rt], 0, 0, 0);
        }

        // ---- gather at C/D coords: pacc += (acc2 + b2)*(e - s*r), all f32 LDS ----
        #pragma unroll
        for (int rt = 0; rt < 2; ++rt) {
            #pragma unroll
            for (int j = 0; j < 4; ++j) {
                int row = rt * 16 + qh * 4 + j;
                int fi  = row * 128 + (((col >> 2) ^ (row & 7)) << 2) + (col & 3);
                float e = bufE[cur][fi];
                float s = bufS[cur][fi];
                float r = bufR[cur][fi];
                pacc += (acc2[rt][j] + b2r) * (e - s * r);
            }
        }

        // ---- per-b tail (odd task): reduce, normalize, store ----
        if (t & 1) {
            float p = pacc;
            p += __shfl_xor(p, 16);
            p += __shfl_xor(p, 32);
            if (qh == 0) sFin[col] = p;
            WG_BARRIER();
            float fv = 0.f, qe = 0.f;
            if (tid < 128) {
                fv = sFin[tid];
                qe = sQe[bb * 128 + tid];
                float rn = fabsf(fv), qn = fabsf(qe);
                #pragma unroll
                for (int off = 1; off < 64; off <<= 1) {
                    rn += __shfl_xor(rn, off);
                    qn += __shfl_xor(qn, off);
                }
                if (lane == 0) { sRed[wv * 2] = rn; sRed[wv * 2 + 1] = qn; }
            }
            WG_BARRIER();
            if (tid < 128) {
                float RN = sRed[0] + sRed[2];
                float QN = sRed[1] + sRed[3];
                float scale = 1.0f / (1e-9f + (RN / QN) * 2.5f);
                out[((size_t)bid * 16 + bb) * 128 + tid] = qe + fv * scale;
            }
            pacc = 0.f;
        }

        WG_BARRIER();   // end-of-iter: buf[cur] reads done before its re-issue
    }
    #undef ISSUE
}

extern "C" void kernel_launch(void* const* d_in, const int* in_sizes, int n_in,
                              void* d_out, int out_size, void* d_ws, size_t ws_size,
                              hipStream_t stream) {
    const float* query_emb  = (const float*)d_in[0];
    const float* refer_embs = (const float*)d_in[1];
    const float* query_r    = (const float*)d_in[2];
    const float* refer_r    = (const float*)d_in[3];
    const float* start_embs = (const float*)d_in[4];
    const float* W1         = (const float*)d_in[5];
    const float* b1         = (const float*)d_in[6];
    const float* W2         = (const float*)d_in[7];
    const float* b2         = (const float*)d_in[8];
    float* out = (float*)d_out;

    char* ws = (char*)d_ws;
    float* qv            = (float*)ws;                              // 4096*128*4 = 2 MB
    unsigned short* w1b  = (unsigned short*)(ws + 2 * 1024 * 1024); // 32 KB
    unsigned short* w2b  = w1b + 16384;                             // 32 KB

    pa_prep<<<128, 256, 0, stream>>>(W1, W2, w1b, w2b);
    pa_qv<<<128, 256, 0, stream>>>(query_r, W1, b1, qv);
    pa_main<<<256, 512, 0, stream>>>(query_emb, refer_embs, refer_r, start_embs,
                                     qv, w1b, w2b, b2, out);
}

// Round 13
// 102.303 us; speedup vs baseline: 1.3255x; 1.3255x over previous
//
#include <hip/hip_runtime.h>
#include <hip/hip_bf16.h>

// ProjectionAggregating: B=4096, N=64, D=128
// out[b,d] = query_emb + final_refer / (1e-9 + ref_norm/query_norm*2.5)
// final_refer[b,d] = sum_n (h1@W2^T + b2)[b,n,d] * (refer_embs - start_embs*refer_r)[b,n,d]
// h1 = relu(query_r@W1a^T + refer_r@W1b^T + b1)   (W1a = W1[:, :128], W1b = W1[:, 128:])
//
// Structure = R4 (best measured, replay-validated). qv is fused into GEMM1 via
// K-extension: A-rows broadcast query_r, B = W1a bf16 -> 8 extra MFMAs/block;
// the separate pa_qv kernel and its 4 MB round-trip are deleted.

typedef __attribute__((ext_vector_type(8))) short bf16x8;   // 8 bf16 = 4 VGPRs (MFMA A/B frag)
typedef __attribute__((ext_vector_type(4))) float f32x4;    // MFMA C/D frag

__device__ __forceinline__ unsigned short f2bf(float x) {      // RNE
    unsigned int u = __float_as_uint(x);
    u += 0x7FFFu + ((u >> 16) & 1u);
    return (unsigned short)(u >> 16);
}
__device__ __forceinline__ float bf2f(unsigned short h) {
    return __uint_as_float(((unsigned int)h) << 16);
}

// ---- kernel 1: convert W1a, W1b, W2 to bf16 into workspace ----
__global__ __launch_bounds__(256) void pa_prep(const float* __restrict__ W1,
                                               const float* __restrict__ W2,
                                               unsigned short* __restrict__ w1a,
                                               unsigned short* __restrict__ w1b,
                                               unsigned short* __restrict__ w2b) {
    int i = blockIdx.x * 256 + threadIdx.x;   // grid covers 49152
    int j = i & 16383;
    int d = j >> 7, k = j & 127;
    if (i < 16384) {
        w1a[j] = f2bf(W1[d * 256 + k]);
    } else if (i < 32768) {
        w1b[j] = f2bf(W1[d * 256 + 128 + k]);
    } else {
        w2b[j] = f2bf(W2[j]);
    }
}

// ---- kernel 2: main fused kernel, one block per b (R4 structure) ----
__global__ __launch_bounds__(256, 2) void pa_main(
    const float* __restrict__ query_emb,
    const float* __restrict__ refer_embs,
    const float* __restrict__ query_r,
    const float* __restrict__ refer_r,
    const float* __restrict__ start_embs,
    const unsigned short* __restrict__ w1a,
    const unsigned short* __restrict__ w1b,
    const unsigned short* __restrict__ w2b,
    const float* __restrict__ b1,
    const float* __restrict__ b2,
    float* __restrict__ out) {
    __shared__ __align__(16) unsigned short sR[64 * 128];  // refer_r bf16 swz (16 KB), persists
    __shared__ __align__(16) unsigned short sH[64 * 128];  // h1 bf16 swz -> attn bf16 (16 KB)
    __shared__ float sPart[8][132];                        // col-partials, padded (4.2 KB)
    __shared__ __align__(16) unsigned short sQr[128];      // query_r bf16 (256 B)
    __shared__ float sRed[4];

    const int b    = blockIdx.x;
    const int tid  = threadIdx.x;
    const int lane = tid & 63;
    const int wv   = tid >> 6;       // 4 waves; wave wv owns output cols [32*wv, 32*wv+32)
    const int hl   = lane & 15;
    const int qh   = lane >> 4;      // quarter-wave index
    const int wcol = wv * 32;

    const size_t base = (size_t)b * 8192;
    const float4* rr4 = (const float4*)(refer_r + base);
    const float4* re4 = (const float4*)(refer_embs + base);
    const float4* se4 = (const float4*)(start_embs + base);

    // ---- convoy 1: refer_r burst + small tail data ----
    float4 rburst[8];
    #pragma unroll
    for (int it = 0; it < 8; ++it) rburst[it] = rr4[tid + it * 256];
    float qe   = (tid < 128) ? query_emb[(size_t)b * 128 + tid] : 0.f;
    float b1v0 = b1[wcol + hl];
    float b1v1 = b1[wcol + 16 + hl];
    float b2v0 = b2[wcol + hl];
    float b2v1 = b2[wcol + 16 + hl];
    bf16x8 bW[2][4], bWa[2][4];
    #pragma unroll
    for (int ct = 0; ct < 2; ++ct)
        #pragma unroll
        for (int ks = 0; ks < 4; ++ks) {
            bW[ct][ks]  = *(const bf16x8*)(w1b + (wcol + ct * 16 + hl) * 128 + ks * 32 + qh * 8);
            bWa[ct][ks] = *(const bf16x8*)(w1a + (wcol + ct * 16 + hl) * 128 + ks * 32 + qh * 8);
        }

    if (tid < 128) sQr[tid] = f2bf(query_r[(size_t)b * 128 + tid]);
    #pragma unroll
    for (int it = 0; it < 8; ++it) {
        int e0  = (tid + it * 256) * 4;
        int row = e0 >> 7;           // = it*8 + (tid>>5)
        int kc  = e0 & 127;          // = (tid&31)*4
        float4 r = rburst[it];
        ushort4 bv;
        bv.x = f2bf(r.x); bv.y = f2bf(r.y); bv.z = f2bf(r.z); bv.w = f2bf(r.w);
        int byte = row * 256 + ((kc * 2) ^ ((row & 7) << 4));
        *(ushort4*)((char*)sR + byte) = bv;
    }
    __syncthreads();   // B1: sR + sQr staged

    // ---- convoy 2: W2 frags + FULL e/s stream (fire-and-forget) ----
    bf16x8 bW2[2][4];
    #pragma unroll
    for (int ct = 0; ct < 2; ++ct)
        #pragma unroll
        for (int ks = 0; ks < 4; ++ks)
            bW2[ct][ks] = *(const bf16x8*)(w2b + (wcol + ct * 16 + hl) * 128 + ks * 32 + qh * 8);
    float4 ge[8], gs[8];
    #pragma unroll
    for (int j = 0; j < 8; ++j) {
        int i = tid + j * 256;
        ge[j] = re4[i];
        gs[j] = se4[i];
    }

    // ---- qv tile: qvacc[ct] = broadcast(query_r) x W1a(cols) ----
    // All A-rows identical -> all D rows identical: qvacc[ct][j] == qv[col].
    f32x4 qvacc[2] = {};
    {
        bf16x8 aq[4];
        #pragma unroll
        for (int ks = 0; ks < 4; ++ks)
            aq[ks] = *(const bf16x8*)(sQr + ks * 32 + qh * 8);
        #pragma unroll
        for (int ct = 0; ct < 2; ++ct)
            #pragma unroll
            for (int ks = 0; ks < 4; ++ks)
                qvacc[ct] = __builtin_amdgcn_mfma_f32_16x16x32_bf16(aq[ks], bWa[ct][ks], qvacc[ct], 0, 0, 0);
    }

    // ---- GEMM1: h1[row,col] = sum_k r[row,k] * W1b[col,k] ----
    f32x4 acc1[4][2] = {};
    #pragma unroll
    for (int rt = 0; rt < 4; ++rt) {
        const int row = rt * 16 + hl;
        const int rsw = (row & 7) << 4;
        bf16x8 af[4];
        #pragma unroll
        for (int ks = 0; ks < 4; ++ks) {
            int byte = row * 256 + ((ks * 64 + qh * 16) ^ rsw);
            af[ks] = *(const bf16x8*)((const char*)sR + byte);
        }
        #pragma unroll
        for (int ct = 0; ct < 2; ++ct)
            #pragma unroll
            for (int ks = 0; ks < 4; ++ks)
                acc1[rt][ct] = __builtin_amdgcn_mfma_f32_16x16x32_bf16(af[ks], bW[ct][ks], acc1[rt][ct], 0, 0, 0);
    }

    // ---- epi1: h1 = relu(acc1 + qv[col] + b1[col]) -> sH ----
    // C/D: col = lane&15, row = (lane>>4)*4 + reg
    #pragma unroll
    for (int ct = 0; ct < 2; ++ct) {
        const int col = wcol + ct * 16 + hl;
        const float bb = (ct == 0) ? b1v0 : b1v1;
        #pragma unroll
        for (int rt = 0; rt < 4; ++rt) {
            #pragma unroll
            for (int j = 0; j < 4; ++j) {
                int row = rt * 16 + qh * 4 + j;
                float h = acc1[rt][ct][j] + qvacc[ct][j] + bb;
                h = h > 0.0f ? h : 0.0f;
                int byte = row * 256 + ((col * 2) ^ ((row & 7) << 4));
                *(unsigned short*)((char*)sH + byte) = f2bf(h);
            }
        }
    }
    __syncthreads();   // B2: h1 ready

    // ---- GEMM2: attn[row,col] = sum_k h1[row,k] * W2[col,k] ----
    f32x4 acc2[4][2] = {};
    #pragma unroll
    for (int rt = 0; rt < 4; ++rt) {
        const int row = rt * 16 + hl;
        const int rsw = (row & 7) << 4;
        bf16x8 af[4];
        #pragma unroll
        for (int ks = 0; ks < 4; ++ks) {
            int byte = row * 256 + ((ks * 64 + qh * 16) ^ rsw);
            af[ks] = *(const bf16x8*)((const char*)sH + byte);
        }
        #pragma unroll
        for (int ct = 0; ct < 2; ++ct)
            #pragma unroll
            for (int ks = 0; ks < 4; ++ks)
                acc2[rt][ct] = __builtin_amdgcn_mfma_f32_16x16x32_bf16(af[ks], bW2[ct][ks], acc2[rt][ct], 0, 0, 0);
    }
    __syncthreads();   // B3: all GEMM2 reads of sH done

    // ---- epi2: attn(+b2) -> sH (same swizzle) ----
    #pragma unroll
    for (int ct = 0; ct < 2; ++ct) {
        const int col = wcol + ct * 16 + hl;
        const float bb = (ct == 0) ? b2v0 : b2v1;
        #pragma unroll
        for (int rt = 0; rt < 4; ++rt) {
            #pragma unroll
            for (int j = 0; j < 4; ++j) {
                int row = rt * 16 + qh * 4 + j;
                int byte = row * 256 + ((col * 2) ^ ((row & 7) << 4));
                *(unsigned short*)((char*)sH + byte) = f2bf(acc2[rt][ct][j] + bb);
            }
        }
    }
    __syncthreads();   // B4: attn ready

    // ---- gather: p += attn * (e - s*r); e/s in registers ----
    const int t  = tid >> 5;          // 0..7: row sub-index, also sPart row
    const int kc = (tid & 31) * 4;    // fixed 4 cols per thread
    float p0 = 0.f, p1 = 0.f, p2 = 0.f, p3 = 0.f;
    #pragma unroll
    for (int j = 0; j < 8; ++j) {
        int row  = j * 8 + t;
        int byte = row * 256 + ((kc * 2) ^ ((row & 7) << 4));
        ushort4 a  = *(const ushort4*)((const char*)sH + byte);
        ushort4 rv = *(const ushort4*)((const char*)sR + byte);
        float4 e = ge[j], s = gs[j];
        p0 += bf2f(a.x) * (e.x - s.x * bf2f(rv.x));
        p1 += bf2f(a.y) * (e.y - s.y * bf2f(rv.y));
        p2 += bf2f(a.z) * (e.z - s.z * bf2f(rv.z));
        p3 += bf2f(a.w) * (e.w - s.w * bf2f(rv.w));
    }
    sPart[t][kc + 0] = p0;
    sPart[t][kc + 1] = p1;
    sPart[t][kc + 2] = p2;
    sPart[t][kc + 3] = p3;
    __syncthreads();   // B5

    // ---- final: row-sum partials, normalize, add query_emb (preloaded) ----
    float fv = 0.f;
    if (tid < 128) {
        #pragma unroll
        for (int r = 0; r < 8; ++r) fv += sPart[r][tid];
        float rn = fabsf(fv), qn = fabsf(qe);
        #pragma unroll
        for (int off = 1; off < 64; off <<= 1) {
            rn += __shfl_xor(rn, off);
            qn += __shfl_xor(qn, off);
        }
        if (lane == 0) { sRed[wv * 2] = rn; sRed[wv * 2 + 1] = qn; }
    }
    __syncthreads();   // B6
    if (tid < 128) {
        float RN = sRed[0] + sRed[2];
        float QN = sRed[1] + sRed[3];
        float scale = 1.0f / (1e-9f + (RN / QN) * 2.5f);
        out[(size_t)b * 128 + tid] = qe + fv * scale;
    }
}

extern "C" void kernel_launch(void* const* d_in, const int* in_sizes, int n_in,
                              void* d_out, int out_size, void* d_ws, size_t ws_size,
                              hipStream_t stream) {
    const float* query_emb  = (const float*)d_in[0];
    const float* refer_embs = (const float*)d_in[1];
    const float* query_r    = (const float*)d_in[2];
    const float* refer_r    = (const float*)d_in[3];
    const float* start_embs = (const float*)d_in[4];
    const float* W1         = (const float*)d_in[5];
    const float* b1         = (const float*)d_in[6];
    const float* W2         = (const float*)d_in[7];
    const float* b2         = (const float*)d_in[8];
    float* out = (float*)d_out;

    unsigned short* w1a = (unsigned short*)d_ws;   // 32 KB
    unsigned short* w1b = w1a + 16384;             // 32 KB
    unsigned short* w2b = w1b + 16384;             // 32 KB

    pa_prep<<<192, 256, 0, stream>>>(W1, W2, w1a, w1b, w2b);
    pa_main<<<4096, 256, 0, stream>>>(query_emb, refer_embs, query_r, refer_r,
                                      start_embs, w1a, w1b, w2b, b1, b2, out);
}